// Round 4
// baseline (415.230 us; speedup 1.0000x reference)
//
#include <hip/hip_runtime.h>

#define D_FEAT 128

// ---- bf16 as raw ushort: explicit round-to-nearest-even pack, shift unpack ----
__device__ __forceinline__ unsigned short f32_to_bf16(float f) {
    unsigned int u = __float_as_uint(f);
    u += 0x7fffu + ((u >> 16) & 1u);        // RNE
    return (unsigned short)(u >> 16);
}
__device__ __forceinline__ float bf16_to_f32(unsigned short h) {
    return __uint_as_float((unsigned int)h << 16);
}

// ---------------- CSR build ----------------

__global__ void hist_kernel(const int* __restrict__ ei, int E,
                            int* __restrict__ deg) {
    int e = blockIdx.x * blockDim.x + threadIdx.x;
    if (e < E) atomicAdd(&deg[ei[e]], 1);   // dst = edge_index[0]
}

// per-block exclusive scan of deg -> rowstart (local), block sums -> bsum.
// Also computes norm[i] = rsqrt(1 + deg[i]).
__global__ void scan_block(const int* __restrict__ deg, int N,
                           int* __restrict__ rowstart, int* __restrict__ bsum,
                           float* __restrict__ norm) {
    __shared__ int s[256];
    int t = threadIdx.x;
    int i = blockIdx.x * 256 + t;
    int v = (i < N) ? deg[i] : 0;
    if (i < N) norm[i] = rsqrtf(1.0f + (float)v);
    s[t] = v;
    __syncthreads();
    for (int o = 1; o < 256; o <<= 1) {
        int x = (t >= o) ? s[t - o] : 0;
        __syncthreads();
        s[t] += x;
        __syncthreads();
    }
    if (i < N) rowstart[i] = s[t] - v;      // exclusive within block
    if (t == 255) bsum[blockIdx.x] = s[255];
}

// single-block exclusive scan of block sums (nb <= 512)
__global__ void scan_top(const int* __restrict__ bsum, int* __restrict__ boff, int nb) {
    __shared__ int s[512];
    int t = threadIdx.x;
    int v = (t < nb) ? bsum[t] : 0;
    s[t] = v;
    __syncthreads();
    for (int o = 1; o < 512; o <<= 1) {
        int x = (t >= o) ? s[t - o] : 0;
        __syncthreads();
        s[t] += x;
        __syncthreads();
    }
    if (t < nb) boff[t] = s[t] - v;
}

__global__ void scan_add(int* __restrict__ rowstart, int* __restrict__ cursor,
                         const int* __restrict__ boff, int N, int E) {
    int i = blockIdx.x * blockDim.x + threadIdx.x;
    if (i < N) {
        int v = rowstart[i] + boff[i >> 8];
        rowstart[i] = v;
        cursor[i] = v;
    }
    if (i == 0) rowstart[N] = E;
}

// place src nodes via cursor atomics (order within a row is non-deterministic;
// only reorders fp sums, far below absmax threshold)
__global__ void scatter_kernel(const int* __restrict__ ei, int E,
                               int* __restrict__ cursor,
                               int* __restrict__ esrc) {
    int e = blockIdx.x * blockDim.x + threadIdx.x;
    if (e < E) {
        int d = ei[e];          // dst
        int s = ei[E + e];      // src
        esrc[atomicAdd(&cursor[d], 1)] = s;
    }
}

// ---------------- f32 -> bf16 convert (8 elements/thread) ----------------
__global__ void cvt_kernel(const float* __restrict__ x,
                           unsigned short* __restrict__ xb, long n) {
    long i = ((long)blockIdx.x * blockDim.x + threadIdx.x) * 8;
    if (i < n) {
        float4 v0 = *(const float4*)(x + i);
        float4 v1 = *(const float4*)(x + i + 4);
        ushort4 o0, o1;
        o0.x = f32_to_bf16(v0.x); o0.y = f32_to_bf16(v0.y);
        o0.z = f32_to_bf16(v0.z); o0.w = f32_to_bf16(v0.w);
        o1.x = f32_to_bf16(v1.x); o1.y = f32_to_bf16(v1.y);
        o1.z = f32_to_bf16(v1.z); o1.w = f32_to_bf16(v1.w);
        *(ushort4*)(xb + i) = o0;
        *(ushort4*)(xb + i + 4) = o1;
    }
}

// ---------------- fused conv, wave-per-row ----------------
// One 64-lane wave per dst row. Half-wave h (lanes 32h..32h+31) processes
// neighbors k = r0+h, r0+h+2, ... Each lane gathers ushort4 = 4 bf16 features;
// 32 lanes x 8B = one full 256B row per load instruction. Halves merged with
// shfl_xor(32). Epilogue on lanes 0-31 (features 4*fl..4*fl+3).
// LAYER 0: self term from f32 x; epilogue +x residual, LayerNorm, write bf16.
// LAYER 1: self term from bf16 hb; epilogue +x, write f32.
template <int LAYER>
__global__ __launch_bounds__(256) void conv2(const float* __restrict__ x,
                                             const unsigned short* __restrict__ hb,
                                             float* __restrict__ out,
                                             unsigned short* __restrict__ outb,
                                             const float* __restrict__ norm,
                                             const int* __restrict__ rowstart,
                                             const int* __restrict__ esrc,
                                             int N) {
    int lane = threadIdx.x & 63;
    int row = blockIdx.x * 4 + (threadIdx.x >> 6);
    if (row >= N) return;
    int r0 = rowstart[row], r1 = rowstart[row + 1];
    int hl = lane >> 5;         // half index 0/1
    int fl = lane & 31;         // feature-lane: owns features 4*fl..4*fl+3
    const ushort4* hb4 = (const ushort4*)hb;

    float a0 = 0.f, a1 = 0.f, a2 = 0.f, a3 = 0.f;
    for (int k = r0 + hl; k < r1; k += 2) {
        int j = esrc[k];                    // broadcast within half-wave
        float nj = norm[j];
        ushort4 h4 = hb4[j * 32 + fl];      // int32 addressing, 8B/lane
        a0 += nj * bf16_to_f32(h4.x);
        a1 += nj * bf16_to_f32(h4.y);
        a2 += nj * bf16_to_f32(h4.z);
        a3 += nj * bf16_to_f32(h4.w);
    }
    // merge even/odd-neighbor halves
    a0 += __shfl_xor(a0, 32);
    a1 += __shfl_xor(a1, 32);
    a2 += __shfl_xor(a2, 32);
    a3 += __shfl_xor(a3, 32);
    if (hl) return;                         // epilogue on lanes 0-31 only

    float ni = norm[row];
    float4 xv = ((const float4*)x)[row * 32 + fl];
    if (LAYER == 0) {
        // o = ni*(sum + ni*x_i) + x_i  (self term in f32), then LayerNorm
        a0 = ni * (a0 + ni * xv.x) + xv.x;
        a1 = ni * (a1 + ni * xv.y) + xv.y;
        a2 = ni * (a2 + ni * xv.z) + xv.z;
        a3 = ni * (a3 + ni * xv.w) + xv.w;
        float s = a0 + a1 + a2 + a3;
        #pragma unroll
        for (int m = 1; m < 32; m <<= 1) s += __shfl_xor(s, m);
        float mean = s * (1.0f / 128.0f);
        a0 -= mean; a1 -= mean; a2 -= mean; a3 -= mean;
        float vs = a0 * a0 + a1 * a1 + a2 * a2 + a3 * a3;
        #pragma unroll
        for (int m = 1; m < 32; m <<= 1) vs += __shfl_xor(vs, m);
        float rs = rsqrtf(vs * (1.0f / 128.0f) + 1e-5f);
        ushort4 o4;
        o4.x = f32_to_bf16(a0 * rs);
        o4.y = f32_to_bf16(a1 * rs);
        o4.z = f32_to_bf16(a2 * rs);
        o4.w = f32_to_bf16(a3 * rs);
        ((ushort4*)outb)[row * 32 + fl] = o4;
    } else {
        ushort4 h4 = hb4[row * 32 + fl];    // self from bf16 h
        float4 o;
        o.x = ni * (a0 + ni * bf16_to_f32(h4.x)) + xv.x;
        o.y = ni * (a1 + ni * bf16_to_f32(h4.y)) + xv.y;
        o.z = ni * (a2 + ni * bf16_to_f32(h4.z)) + xv.z;
        o.w = ni * (a3 + ni * bf16_to_f32(h4.w)) + xv.w;
        ((float4*)out)[row * 32 + fl] = o;
    }
}

// ---------------- launch ----------------

extern "C" void kernel_launch(void* const* d_in, const int* in_sizes, int n_in,
                              void* d_out, int out_size, void* d_ws, size_t ws_size,
                              hipStream_t stream) {
    const float* x = (const float*)d_in[0];
    const int* ei = (const int*)d_in[1];
    int N = in_sizes[0] / D_FEAT;
    int E = in_sizes[1] / 2;
    float* out = (float*)d_out;

    char* ws = (char*)d_ws;
    size_t off = 0;
    auto alloc = [&](size_t bytes) -> void* {
        size_t cur = (off + 511) & ~(size_t)511;
        off = cur + bytes;
        return (void*)(ws + cur);
    };
    int* deg             = (int*)alloc((size_t)N * 4);
    int* rowstart        = (int*)alloc((size_t)(N + 1) * 4);
    int* cursor          = (int*)alloc((size_t)N * 4);
    int* esrc            = (int*)alloc((size_t)E * 4);
    float* norm          = (float*)alloc((size_t)N * 4);
    unsigned short* xb16 = (unsigned short*)alloc((size_t)N * D_FEAT * 2);
    unsigned short* h2b  = (unsigned short*)alloc((size_t)N * D_FEAT * 2);
    int* bsum            = (int*)alloc(1024 * 4);
    int* boff            = (int*)alloc(1024 * 4);
    (void)ws_size; (void)n_in; (void)out_size;

    (void)hipMemsetAsync(deg, 0, (size_t)N * 4, stream);

    int eb = (E + 255) / 256;
    hist_kernel<<<eb, 256, 0, stream>>>(ei, E, deg);

    int nb = (N + 255) / 256;                 // 391 for N=100000, <=512
    scan_block<<<nb, 256, 0, stream>>>(deg, N, rowstart, bsum, norm);
    scan_top<<<1, 512, 0, stream>>>(bsum, boff, nb);
    scan_add<<<nb, 256, 0, stream>>>(rowstart, cursor, boff, N, E);
    scatter_kernel<<<eb, 256, 0, stream>>>(ei, E, cursor, esrc);

    long n = (long)N * D_FEAT;
    cvt_kernel<<<(int)((n / 8 + 255) / 256), 256, 0, stream>>>(x, xb16, n);

    // layer 0: h2b = bf16( LN( conv(x) + x ) )
    conv2<0><<<(N + 3) / 4, 256, 0, stream>>>(x, xb16, nullptr, h2b, norm, rowstart, esrc, N);
    // layer 1: out = conv(h2b) + x
    conv2<1><<<(N + 3) / 4, 256, 0, stream>>>(x, h2b, out, nullptr, norm, rowstart, esrc, N);
}

// Round 5
// 337.170 us; speedup vs baseline: 1.2315x; 1.2315x over previous
//
#include <hip/hip_runtime.h>

#define D_FEAT 128

// ---- bf16 as raw ushort: explicit round-to-nearest-even pack, shift unpack ----
__device__ __forceinline__ unsigned short f32_to_bf16(float f) {
    unsigned int u = __float_as_uint(f);
    u += 0x7fffu + ((u >> 16) & 1u);        // RNE
    return (unsigned short)(u >> 16);
}

// ---------------- CSR build (two-pass, proven in R3) ----------------

__global__ void hist_kernel(const int* __restrict__ ei, int E,
                            int* __restrict__ deg, int* __restrict__ pos) {
    int e = blockIdx.x * blockDim.x + threadIdx.x;
    if (e < E) {
        int d = ei[e];                      // dst = edge_index[0]
        pos[e] = atomicAdd(&deg[d], 1);
    }
}

__global__ void scan_block(const int* __restrict__ deg, int N,
                           int* __restrict__ rowstart, int* __restrict__ bsum,
                           float* __restrict__ norm) {
    __shared__ int s[256];
    int t = threadIdx.x;
    int i = blockIdx.x * 256 + t;
    int v = (i < N) ? deg[i] : 0;
    if (i < N) norm[i] = rsqrtf(1.0f + (float)v);
    s[t] = v;
    __syncthreads();
    for (int o = 1; o < 256; o <<= 1) {
        int x = (t >= o) ? s[t - o] : 0;
        __syncthreads();
        s[t] += x;
        __syncthreads();
    }
    if (i < N) rowstart[i] = s[t] - v;      // exclusive within block
    if (t == 255) bsum[blockIdx.x] = s[255];
}

__global__ void scan_top(const int* __restrict__ bsum, int* __restrict__ boff, int nb) {
    __shared__ int s[512];
    int t = threadIdx.x;
    int v = (t < nb) ? bsum[t] : 0;
    s[t] = v;
    __syncthreads();
    for (int o = 1; o < 512; o <<= 1) {
        int x = (t >= o) ? s[t - o] : 0;
        __syncthreads();
        s[t] += x;
        __syncthreads();
    }
    if (t < nb) boff[t] = s[t] - v;
}

__global__ void scan_add(int* __restrict__ rowstart, const int* __restrict__ boff,
                         int N, int E) {
    int i = blockIdx.x * blockDim.x + threadIdx.x;
    if (i < N) rowstart[i] += boff[i >> 8];
    if (i == 0) rowstart[N] = E;
}

__global__ void scatter_kernel(const int* __restrict__ ei, int E,
                               const int* __restrict__ rowstart,
                               const int* __restrict__ pos,
                               int* __restrict__ esrc) {
    int e = blockIdx.x * blockDim.x + threadIdx.x;
    if (e < E) {
        int d = ei[e];          // dst
        int s = ei[E + e];      // src
        esrc[rowstart[d] + pos[e]] = s;
    }
}

// ---------------- f32 -> bf16 convert (8 elements/thread) ----------------
__global__ void cvt_kernel(const float* __restrict__ x,
                           unsigned short* __restrict__ xb, long n) {
    long i = ((long)blockIdx.x * blockDim.x + threadIdx.x) * 8;
    if (i < n) {
        float4 v0 = *(const float4*)(x + i);
        float4 v1 = *(const float4*)(x + i + 4);
        ushort4 o0, o1;
        o0.x = f32_to_bf16(v0.x); o0.y = f32_to_bf16(v0.y);
        o0.z = f32_to_bf16(v0.z); o0.w = f32_to_bf16(v0.w);
        o1.x = f32_to_bf16(v1.x); o1.y = f32_to_bf16(v1.y);
        o1.z = f32_to_bf16(v1.z); o1.w = f32_to_bf16(v1.w);
        *(ushort4*)(xb + i) = o0;
        *(ushort4*)(xb + i + 4) = o1;
    }
}

// ---------------- fused conv, wave-per-row, shfl-staged neighbor list ----------------
// One 64-lane wave per dst row. Stage <=64 (j, norm[j]) pairs into lane regs with
// one coalesced esrc load + one norm gather; inner loop broadcasts (j,nj) via
// __shfl so every hb row-gather is immediately issuable (no dependent-load chain).
// Each lane owns 2 features packed as ushort2-in-uint (64 lanes x 4B = 256B row).
// LAYER 0: self from f32 x; epilogue +x residual, LayerNorm, write bf16.
// LAYER 1: self from bf16 hb; epilogue +x, write f32.
template <int LAYER>
__global__ __launch_bounds__(256) void conv3(const float* __restrict__ x,
                                             const unsigned short* __restrict__ hb,
                                             float* __restrict__ out,
                                             unsigned short* __restrict__ outb,
                                             const float* __restrict__ norm,
                                             const int* __restrict__ rowstart,
                                             const int* __restrict__ esrc,
                                             int N) {
    int lane = threadIdx.x & 63;
    int row = blockIdx.x * 4 + (threadIdx.x >> 6);
    if (row >= N) return;
    int r0 = rowstart[row], r1 = rowstart[row + 1];
    const unsigned int* hb2 = (const unsigned int*)hb;  // 2 bf16 per uint

    float a0 = 0.f, a1 = 0.f;
    for (int base = r0; base < r1; base += 64) {
        int kk = base + lane;
        int jreg = 0;
        float nreg = 0.f;
        if (kk < r1) {
            jreg = esrc[kk];                // one coalesced load per 64 neighbors
            nreg = norm[jreg];              // one gathered load
        }
        int cnt = min(64, r1 - base);
        for (int q = 0; q < cnt; ++q) {
            int j = __shfl(jreg, q, 64);    // broadcast, no memory dependency
            float nj = __shfl(nreg, q, 64);
            unsigned int h2 = hb2[j * 64 + lane];     // 256B coalesced row gather
            a0 += nj * __uint_as_float(h2 << 16);          // feature 2*lane
            a1 += nj * __uint_as_float(h2 & 0xffff0000u);  // feature 2*lane+1
        }
    }

    float ni = norm[row];
    float2 xv = ((const float2*)x)[row * 64 + lane];
    if (LAYER == 0) {
        // o = ni*(sum + ni*x_i) + x_i, then affine-free LayerNorm, write bf16
        a0 = ni * (a0 + ni * xv.x) + xv.x;
        a1 = ni * (a1 + ni * xv.y) + xv.y;
        float s = a0 + a1;
        #pragma unroll
        for (int m = 1; m < 64; m <<= 1) s += __shfl_xor(s, m);
        float mean = s * (1.0f / 128.0f);
        a0 -= mean; a1 -= mean;
        float vs = a0 * a0 + a1 * a1;
        #pragma unroll
        for (int m = 1; m < 64; m <<= 1) vs += __shfl_xor(vs, m);
        float rs = rsqrtf(vs * (1.0f / 128.0f) + 1e-5f);
        unsigned int o = (unsigned int)f32_to_bf16(a0 * rs)
                       | ((unsigned int)f32_to_bf16(a1 * rs) << 16);
        ((unsigned int*)outb)[row * 64 + lane] = o;
    } else {
        unsigned int h2 = hb2[row * 64 + lane];       // self from bf16 h
        float o0 = ni * (a0 + ni * __uint_as_float(h2 << 16)) + xv.x;
        float o1 = ni * (a1 + ni * __uint_as_float(h2 & 0xffff0000u)) + xv.y;
        ((float2*)out)[row * 64 + lane] = make_float2(o0, o1);
    }
}

// ---------------- launch ----------------

extern "C" void kernel_launch(void* const* d_in, const int* in_sizes, int n_in,
                              void* d_out, int out_size, void* d_ws, size_t ws_size,
                              hipStream_t stream) {
    const float* x = (const float*)d_in[0];
    const int* ei = (const int*)d_in[1];
    int N = in_sizes[0] / D_FEAT;
    int E = in_sizes[1] / 2;
    float* out = (float*)d_out;

    char* ws = (char*)d_ws;
    size_t off = 0;
    auto alloc = [&](size_t bytes) -> void* {
        size_t cur = (off + 511) & ~(size_t)511;
        off = cur + bytes;
        return (void*)(ws + cur);
    };
    int* deg             = (int*)alloc((size_t)N * 4);
    int* rowstart        = (int*)alloc((size_t)(N + 1) * 4);
    int* pos             = (int*)alloc((size_t)E * 4);
    int* esrc            = (int*)alloc((size_t)E * 4);
    float* norm          = (float*)alloc((size_t)N * 4);
    unsigned short* xb16 = (unsigned short*)alloc((size_t)N * D_FEAT * 2);
    unsigned short* h2b  = (unsigned short*)alloc((size_t)N * D_FEAT * 2);
    int* bsum            = (int*)alloc(1024 * 4);
    int* boff            = (int*)alloc(1024 * 4);
    (void)ws_size; (void)n_in; (void)out_size;

    (void)hipMemsetAsync(deg, 0, (size_t)N * 4, stream);

    int eb = (E + 255) / 256;
    hist_kernel<<<eb, 256, 0, stream>>>(ei, E, deg, pos);

    int nb = (N + 255) / 256;                 // 391 for N=100000, <=512
    scan_block<<<nb, 256, 0, stream>>>(deg, N, rowstart, bsum, norm);
    scan_top<<<1, 512, 0, stream>>>(bsum, boff, nb);
    scan_add<<<nb, 256, 0, stream>>>(rowstart, boff, N, E);
    scatter_kernel<<<eb, 256, 0, stream>>>(ei, E, rowstart, pos, esrc);

    long n = (long)N * D_FEAT;
    cvt_kernel<<<(int)((n / 8 + 255) / 256), 256, 0, stream>>>(x, xb16, n);

    // layer 0: h2b = bf16( LN( conv(x) + x ) )
    conv3<0><<<(N + 3) / 4, 256, 0, stream>>>(x, xb16, nullptr, h2b, norm, rowstart, esrc, N);
    // layer 1: out = conv(h2b) + x
    conv3<1><<<(N + 3) / 4, 256, 0, stream>>>(x, h2b, out, nullptr, norm, rowstart, esrc, N);
}

// Round 6
// 252.459 us; speedup vs baseline: 1.6447x; 1.3355x over previous
//
#include <hip/hip_runtime.h>

#define D_FEAT 128

// ---- bf16 as raw ushort: explicit round-to-nearest-even pack, shift unpack ----
__device__ __forceinline__ unsigned short f32_to_bf16(float f) {
    unsigned int u = __float_as_uint(f);
    u += 0x7fffu + ((u >> 16) & 1u);        // RNE
    return (unsigned short)(u >> 16);
}

// ---------------- CSR build (two-pass, proven in R3) ----------------

__global__ void hist_kernel(const int* __restrict__ ei, int E,
                            int* __restrict__ deg, int* __restrict__ pos) {
    int e = blockIdx.x * blockDim.x + threadIdx.x;
    if (e < E) {
        int d = ei[e];                      // dst = edge_index[0]
        pos[e] = atomicAdd(&deg[d], 1);
    }
}

__global__ void scan_block(const int* __restrict__ deg, int N,
                           int* __restrict__ rowstart, int* __restrict__ bsum,
                           float* __restrict__ norm) {
    __shared__ int s[256];
    int t = threadIdx.x;
    int i = blockIdx.x * 256 + t;
    int v = (i < N) ? deg[i] : 0;
    if (i < N) norm[i] = rsqrtf(1.0f + (float)v);
    s[t] = v;
    __syncthreads();
    for (int o = 1; o < 256; o <<= 1) {
        int x = (t >= o) ? s[t - o] : 0;
        __syncthreads();
        s[t] += x;
        __syncthreads();
    }
    if (i < N) rowstart[i] = s[t] - v;      // exclusive within block
    if (t == 255) bsum[blockIdx.x] = s[255];
}

__global__ void scan_top(const int* __restrict__ bsum, int* __restrict__ boff, int nb) {
    __shared__ int s[512];
    int t = threadIdx.x;
    int v = (t < nb) ? bsum[t] : 0;
    s[t] = v;
    __syncthreads();
    for (int o = 1; o < 512; o <<= 1) {
        int x = (t >= o) ? s[t - o] : 0;
        __syncthreads();
        s[t] += x;
        __syncthreads();
    }
    if (t < nb) boff[t] = s[t] - v;
}

__global__ void scan_add(int* __restrict__ rowstart, const int* __restrict__ boff,
                         int N, int E) {
    int i = blockIdx.x * blockDim.x + threadIdx.x;
    if (i < N) rowstart[i] += boff[i >> 8];
    if (i == 0) rowstart[N] = E;
}

__global__ void scatter_kernel(const int* __restrict__ ei, int E,
                               const int* __restrict__ rowstart,
                               const int* __restrict__ pos,
                               int* __restrict__ esrc) {
    int e = blockIdx.x * blockDim.x + threadIdx.x;
    if (e < E) {
        int d = ei[e];          // dst
        int s = ei[E + e];      // src
        esrc[rowstart[d] + pos[e]] = s;
    }
}

// ---------------- f32 -> bf16 convert (8 elements/thread) ----------------
__global__ void cvt_kernel(const float* __restrict__ x,
                           unsigned short* __restrict__ xb, long n) {
    long i = ((long)blockIdx.x * blockDim.x + threadIdx.x) * 8;
    if (i < n) {
        float4 v0 = *(const float4*)(x + i);
        float4 v1 = *(const float4*)(x + i + 4);
        ushort4 o0, o1;
        o0.x = f32_to_bf16(v0.x); o0.y = f32_to_bf16(v0.y);
        o0.z = f32_to_bf16(v0.z); o0.w = f32_to_bf16(v0.w);
        o1.x = f32_to_bf16(v1.x); o1.y = f32_to_bf16(v1.y);
        o1.z = f32_to_bf16(v1.z); o1.w = f32_to_bf16(v1.w);
        *(ushort4*)(xb + i) = o0;
        *(ushort4*)(xb + i + 4) = o1;
    }
}

// ---------------- fused conv, wave-per-row, batched-MLP gather ----------------
// One 64-lane wave per dst row. Stage <=64 (j, norm[j]) pairs into lane regs
// (one coalesced esrc load + one norm gather per 64 neighbors). Inner loop is
// unrolled 8-wide: 8 readlane broadcasts -> 8 INDEPENDENT row-gathers issued
// back-to-back -> 8 fma pairs. Lanes past cnt hold j=0/nj=0, so over-issue
// gathers the L1-hot row 0 and adds exact zeros (no branches in the batch).
// Each lane owns 2 features packed as ushort2-in-uint (64 lanes x 4B = 256B row).
// LAYER 0: self from f32 x; epilogue +x residual, LayerNorm, write bf16.
// LAYER 1: self from bf16 hb; epilogue +x, write f32.
template <int LAYER>
__global__ __launch_bounds__(256) void conv4(const float* __restrict__ x,
                                             const unsigned short* __restrict__ hb,
                                             float* __restrict__ out,
                                             unsigned short* __restrict__ outb,
                                             const float* __restrict__ norm,
                                             const int* __restrict__ rowstart,
                                             const int* __restrict__ esrc,
                                             int N) {
    int lane = threadIdx.x & 63;
    int row = blockIdx.x * 4 + (threadIdx.x >> 6);
    if (row >= N) return;
    int r0 = rowstart[row], r1 = rowstart[row + 1];
    const unsigned int* hb2 = (const unsigned int*)hb;  // 2 bf16 per uint

    float a0 = 0.f, a1 = 0.f;
    for (int base = r0; base < r1; base += 64) {
        int kk = base + lane;
        int jreg = 0;
        float nreg = 0.f;
        if (kk < r1) {
            jreg = esrc[kk];                // one coalesced load per 64 neighbors
            nreg = norm[jreg];              // one gathered load
        }
        int cnt = min(64, r1 - base);
        for (int qb = 0; qb < cnt; qb += 8) {
            unsigned int h[8];
            float nj[8];
            #pragma unroll
            for (int u = 0; u < 8; ++u) {
                int j = __builtin_amdgcn_readlane(jreg, qb + u);         // SGPR
                nj[u] = __uint_as_float(
                    __builtin_amdgcn_readlane(__float_as_uint(nreg), qb + u));
                h[u] = hb2[j * 64 + lane];  // independent: 8 loads in flight
            }
            #pragma unroll
            for (int u = 0; u < 8; ++u) {
                a0 += nj[u] * __uint_as_float(h[u] << 16);
                a1 += nj[u] * __uint_as_float(h[u] & 0xffff0000u);
            }
        }
    }

    float ni = norm[row];
    float2 xv = ((const float2*)x)[row * 64 + lane];
    if (LAYER == 0) {
        // o = ni*(sum + ni*x_i) + x_i, then affine-free LayerNorm, write bf16
        a0 = ni * (a0 + ni * xv.x) + xv.x;
        a1 = ni * (a1 + ni * xv.y) + xv.y;
        float s = a0 + a1;
        #pragma unroll
        for (int m = 1; m < 64; m <<= 1) s += __shfl_xor(s, m);
        float mean = s * (1.0f / 128.0f);
        a0 -= mean; a1 -= mean;
        float vs = a0 * a0 + a1 * a1;
        #pragma unroll
        for (int m = 1; m < 64; m <<= 1) vs += __shfl_xor(vs, m);
        float rs = rsqrtf(vs * (1.0f / 128.0f) + 1e-5f);
        unsigned int o = (unsigned int)f32_to_bf16(a0 * rs)
                       | ((unsigned int)f32_to_bf16(a1 * rs) << 16);
        ((unsigned int*)outb)[row * 64 + lane] = o;
    } else {
        unsigned int h2 = hb2[row * 64 + lane];       // self from bf16 h
        float o0 = ni * (a0 + ni * __uint_as_float(h2 << 16)) + xv.x;
        float o1 = ni * (a1 + ni * __uint_as_float(h2 & 0xffff0000u)) + xv.y;
        ((float2*)out)[row * 64 + lane] = make_float2(o0, o1);
    }
}

// ---------------- launch ----------------

extern "C" void kernel_launch(void* const* d_in, const int* in_sizes, int n_in,
                              void* d_out, int out_size, void* d_ws, size_t ws_size,
                              hipStream_t stream) {
    const float* x = (const float*)d_in[0];
    const int* ei = (const int*)d_in[1];
    int N = in_sizes[0] / D_FEAT;
    int E = in_sizes[1] / 2;
    float* out = (float*)d_out;

    char* ws = (char*)d_ws;
    size_t off = 0;
    auto alloc = [&](size_t bytes) -> void* {
        size_t cur = (off + 511) & ~(size_t)511;
        off = cur + bytes;
        return (void*)(ws + cur);
    };
    int* deg             = (int*)alloc((size_t)N * 4);
    int* rowstart        = (int*)alloc((size_t)(N + 1) * 4);
    int* pos             = (int*)alloc((size_t)E * 4);
    int* esrc            = (int*)alloc((size_t)E * 4);
    float* norm          = (float*)alloc((size_t)N * 4);
    unsigned short* xb16 = (unsigned short*)alloc((size_t)N * D_FEAT * 2);
    unsigned short* h2b  = (unsigned short*)alloc((size_t)N * D_FEAT * 2);
    int* bsum            = (int*)alloc(1024 * 4);
    int* boff            = (int*)alloc(1024 * 4);
    (void)ws_size; (void)n_in; (void)out_size;

    (void)hipMemsetAsync(deg, 0, (size_t)N * 4, stream);

    int eb = (E + 255) / 256;
    hist_kernel<<<eb, 256, 0, stream>>>(ei, E, deg, pos);

    int nb = (N + 255) / 256;                 // 391 for N=100000, <=512
    scan_block<<<nb, 256, 0, stream>>>(deg, N, rowstart, bsum, norm);
    scan_top<<<1, 512, 0, stream>>>(bsum, boff, nb);
    scan_add<<<nb, 256, 0, stream>>>(rowstart, boff, N, E);
    scatter_kernel<<<eb, 256, 0, stream>>>(ei, E, rowstart, pos, esrc);

    long n = (long)N * D_FEAT;
    cvt_kernel<<<(int)((n / 8 + 255) / 256), 256, 0, stream>>>(x, xb16, n);

    // layer 0: h2b = bf16( LN( conv(x) + x ) )
    conv4<0><<<(N + 3) / 4, 256, 0, stream>>>(x, xb16, nullptr, h2b, norm, rowstart, esrc, N);
    // layer 1: out = conv(h2b) + x
    conv4<1><<<(N + 3) / 4, 256, 0, stream>>>(x, h2b, out, nullptr, norm, rowstart, esrc, N);
}